// Round 1
// baseline (525.874 us; speedup 1.0000x reference)
//
#include <hip/hip_runtime.h>
#include <stdint.h>

// Problem constants
#define DD  128     // latent dim
#define HH  132     // FCBlock hidden width
#define BB  65536   // batch
#define KKC 8       // num components
#define SW  136     // row stride (elems) for K=128 weight arrays (L0)
#define SH  168     // row stride (elems) for K=160 weight arrays (hidden)
#define SA  152     // act row stride (elems): cols 0..143 real, 144..151 zero

typedef short bf16x8 __attribute__((ext_vector_type(8)));
typedef short bf16x4 __attribute__((ext_vector_type(4)));
typedef float f32x4  __attribute__((ext_vector_type(4)));

__device__ __forceinline__ unsigned short f2b(float f){
  union{float f; unsigned u;} c; c.f = f;
  unsigned r = c.u + 0x7fffu + ((c.u >> 16) & 1u);   // RNE
  return (unsigned short)(r >> 16);
}

// ---------------- prep A: Wf = Wu @ Wm (fp32), bfv = K*(Wu@bm) + bu ----------------
__global__ void prepA(const float* __restrict__ Wm, const float* __restrict__ bm,
                      const float* __restrict__ Wu, const float* __restrict__ bu,
                      float* __restrict__ Wf, float* __restrict__ bfv){
  int idx = blockIdx.x * 256 + threadIdx.x;      // 64 blocks -> 16384 = 128*128
  int i = idx >> 7, j = idx & 127;
  float acc = 0.f;
  for(int d = 0; d < DD; ++d)
    acc += Wu[i*DD + d] * Wm[d*DD + j];
  Wf[idx] = acc;
  if(j == 0){
    float a = 0.f;
    for(int d = 0; d < DD; ++d) a += Wu[i*DD + d] * bm[d];
    bfv[i] = (float)KKC * a + bu[i];
  }
}

// ---------------- prep B: fused + padded + re-strided bf16 weights ----------------
// wAB = [w0s (20480 el, rows 144 x stride 136) | w0r (same)]
// w1p/w2p: 24576 el, rows 144 x stride 168 (cols >=132 zero)
// w3p:     24576 el, rows 128 x stride 168
__global__ void prepB(const float* __restrict__ W0, const float* __restrict__ b0,
                      const float* __restrict__ W1, const float* __restrict__ b1,
                      const float* __restrict__ W2, const float* __restrict__ b2,
                      const float* __restrict__ W3, const float* __restrict__ b3,
                      const float* __restrict__ Wf, const float* __restrict__ bfv,
                      unsigned short* __restrict__ wAB,
                      unsigned short* __restrict__ w1p, unsigned short* __restrict__ w2p,
                      unsigned short* __restrict__ w3p,
                      float* __restrict__ b0p, float* __restrict__ b1p,
                      float* __restrict__ b2p, float* __restrict__ b3p){
  int idx = blockIdx.x * 256 + threadIdx.x;
  if(idx < 20480){                                  // w0s: signal half of W0
    int n = idx / SW, c = idx % SW;
    wAB[idx] = (n < HH && c < DD) ? f2b(W0[n*(2*DD) + c]) : (unsigned short)0;
    return;
  }
  idx -= 20480;
  if(idx < 20480){                                  // w0r = W0r @ Wf
    int n = idx / SW, c = idx % SW;
    float acc = 0.f;
    bool live = (n < HH && c < DD);
    if(live)
      for(int i = 0; i < DD; ++i)
        acc += W0[n*(2*DD) + DD + i] * Wf[i*DD + c];
    wAB[20480 + idx] = live ? f2b(acc) : (unsigned short)0;
    return;
  }
  idx -= 20480;
  if(idx < 24576){                                  // w1p
    int n = idx / SH, c = idx % SH;
    w1p[idx] = (n < HH && c < HH) ? f2b(W1[n*HH + c]) : (unsigned short)0;
    return;
  }
  idx -= 24576;
  if(idx < 24576){                                  // w2p
    int n = idx / SH, c = idx % SH;
    w2p[idx] = (n < HH && c < HH) ? f2b(W2[n*HH + c]) : (unsigned short)0;
    return;
  }
  idx -= 24576;
  if(idx < 24576){                                  // w3p
    int n = idx / SH, c = idx % SH;
    w3p[idx] = (n < DD && c < HH) ? f2b(W3[n*HH + c]) : (unsigned short)0;
    return;
  }
  idx -= 24576;
  if(idx < 144){                                    // b0p = b0 + W0r @ bfv
    float acc = 0.f;
    if(idx < HH){
      acc = b0[idx];
      for(int i = 0; i < DD; ++i) acc += W0[idx*(2*DD) + DD + i] * bfv[i];
    }
    b0p[idx] = acc;
    return;
  }
  idx -= 144;
  if(idx < 144){ b1p[idx] = (idx < HH) ? b1[idx] : 0.f; return; }
  idx -= 144;
  if(idx < 144){ b2p[idx] = (idx < HH) ? b2[idx] : 0.f; return; }
  idx -= 144;
  if(idx < DD){ b3p[idx] = b3[idx]; return; }
}

// ---- async global->LDS: one call = this wave copies 1024B (lane*16 each) ----
__device__ __forceinline__ void stage_copy(const void* gsrc, void* ldst,
                                           int ncalls, int wave, int lane){
  const unsigned char* g = (const unsigned char*)gsrc + lane*16;
  unsigned char* l = (unsigned char*)ldst;
  for(int c = wave; c < ncalls; c += 8){
    __builtin_amdgcn_global_load_lds(
      (const __attribute__((address_space(1))) unsigned int*)(g + c*1024),
      (__attribute__((address_space(3))) unsigned int*)(l + c*1024),
      16, 0, 0);
  }
}

// ---------------- fused: component-sum + 4-layer MLP, one pass over HBM ------------
// 512 threads = 8 waves, 128 rows/block, grid 512, 2 blocks/CU (LDS 71712, VGPR<=128).
// Component sum (256 MB stream) is row-local -> computed in-register here; sumb and
// the comp_sum kernel are gone (-33 MB HBM, -1 dispatch).
// Weights staged in 48-row slices via global_load_lds: L0 = 3 slices single-buffered
// (slice0 issued at kernel start, hidden under the comp stream); L1..L3 = 9 slices
// double-buffered (issue slice j+1, compute slice j, __syncthreads drains the DMA).
// LDS: [0,32768) weight slices; [32768,71680) act (8 waves x 16 x 152); [71680,+32) zeros.
__global__ __launch_bounds__(512, 4) void fused_all(
    const float* __restrict__ signal,
    const float* __restrict__ comps,
    const unsigned short* __restrict__ wAB,
    const unsigned short* __restrict__ w1p,
    const unsigned short* __restrict__ w2p,
    const unsigned short* __restrict__ w3p,
    const float* __restrict__ b0p, const float* __restrict__ b1p,
    const float* __restrict__ b2p, const float* __restrict__ b3p,
    float* __restrict__ out)
{
  __shared__ __align__(16) unsigned char lds[71712];
  unsigned short* R   = (unsigned short*)lds;              // weight slices
  unsigned short* ACT = (unsigned short*)(lds + 32768);    // activations
  unsigned short* ZB  = (unsigned short*)(lds + 71680);    // 16 zero bf16

  const int t    = threadIdx.x;       // 0..511
  const int lane = t & 63;
  const int wave = t >> 6;            // 0..7
  const int m    = lane & 15;
  const int quad = lane >> 4;
  const int rowBase = blockIdx.x * 128 + wave * 16;
  const int arow = rowBase + m;
  unsigned short* actW = ACT + wave * 16 * SA;   // per-wave private 16x152 tile

  // issue L0 slice 0 (w0s rows 0..47 -> R[0,13312); w0r rows 0..47 -> R[13312,26624))
  stage_copy((const char*)wAB,          lds,          13, wave, lane);
  stage_copy((const char*)wAB + 40960,  lds + 13312,  13, wave, lane);

  // ---- component sum (fp32 accumulate, same order as old comp_sum) ----
  f32x4 cs[8];
  #pragma unroll
  for(int i = 0; i < 8; ++i) cs[i] = (f32x4){0.f,0.f,0.f,0.f};
  {
    const float* crow = comps + (size_t)arow * DD + quad*8;
    #pragma unroll
    for(int k = 0; k < KKC; ++k){
      const float* p = crow + (size_t)k * BB * DD;
      #pragma unroll
      for(int ki = 0; ki < 4; ++ki){
        cs[2*ki]   += *(const f32x4*)(p + ki*32);
        cs[2*ki+1] += *(const f32x4*)(p + ki*32 + 4);
      }
    }
  }
  bf16x8 sumf[4];
  #pragma unroll
  for(int ki = 0; ki < 4; ++ki){
    bf16x8 pk;
    #pragma unroll
    for(int j = 0; j < 4; ++j){ pk[j] = (short)f2b(cs[2*ki][j]); pk[4+j] = (short)f2b(cs[2*ki+1][j]); }
    sumf[ki] = pk;
  }

  // ---- signal fragment ----
  bf16x8 sigf[4];
  {
    const float* srow = signal + (size_t)arow * DD + quad*8;
    #pragma unroll
    for(int ki = 0; ki < 4; ++ki){
      f32x4 a = *(const f32x4*)(srow + ki*32);
      f32x4 b = *(const f32x4*)(srow + ki*32 + 4);
      bf16x8 pk;
      #pragma unroll
      for(int j = 0; j < 4; ++j){ pk[j] = (short)f2b(a[j]); pk[4+j] = (short)f2b(b[j]); }
      sigf[ki] = pk;
    }
  }

  // zero act pad cols [144,152) (128 rows x 8 cols = 512 uint writes) + zero buffer
  {
    int row = t >> 2, p = t & 3;
    *(unsigned*)(lds + 32768 + row*(SA*2) + 288 + p*4) = 0u;
    if(t < 8) ((unsigned*)ZB)[t] = 0u;
  }

  __syncthreads();   // drains L0 slice0 DMA + comp loads; publishes zeros

  // ---- layer 0: 3 slices of 48 rows, single-buffered ----
  #pragma unroll
  for(int s = 0; s < 3; ++s){
    #pragma unroll
    for(int jj = 0; jj < 3; ++jj){
      const int r  = jj*16 + m;          // row within slice
      const int rb = s*48 + jj*16 + m;   // global weight row / act col
      f32x4 acc = {0.f,0.f,0.f,0.f};
      #pragma unroll
      for(int ki = 0; ki < 4; ++ki){
        bf16x8 wf = *(const bf16x8*)(R + r*SW + ki*32 + quad*8);
        acc = __builtin_amdgcn_mfma_f32_16x16x32_bf16(sigf[ki], wf, acc, 0, 0, 0);
      }
      #pragma unroll
      for(int ki = 0; ki < 4; ++ki){
        bf16x8 wf = *(const bf16x8*)(R + 6656 + r*SW + ki*32 + quad*8);
        acc = __builtin_amdgcn_mfma_f32_16x16x32_bf16(sumf[ki], wf, acc, 0, 0, 0);
      }
      float bias = b0p[rb];
      #pragma unroll
      for(int rr = 0; rr < 4; ++rr){
        float v = acc[rr] + bias;
        v = v > 0.f ? v : 0.f;
        actW[(quad*4 + rr)*SA + rb] = f2b(v);
      }
    }
    __syncthreads();                     // all waves done reading R
    if(s == 0){
      stage_copy((const char*)wAB + 13056,          lds,         13, wave, lane);
      stage_copy((const char*)wAB + 40960 + 13056,  lds + 13312, 13, wave, lane);
    } else if(s == 1){
      stage_copy((const char*)wAB + 26112,          lds,         13, wave, lane);
      stage_copy((const char*)wAB + 40960 + 26112,  lds + 13312, 13, wave, lane);
    } else {
      stage_copy((const char*)w1p, lds, 16, wave, lane);   // L1 slice0 -> buf0
    }
    __syncthreads();                     // drains the DMA just issued
  }

  // ---- hidden layers: 9 slices (L1 s0..2, L2 s0..2, L3 s0..2), double-buffered ----
  bf16x8 hf[5];
  #pragma unroll
  for(int j = 0; j < 9; ++j){
    const int layer = j / 3, sub = j - layer*3;
    // issue slice j+1 into the other buffer (overlaps with compute below)
    if(j < 8){
      const int nl = (j+1) / 3, ns = (j+1) - nl*3;
      const unsigned short* src = (nl == 0) ? w1p : (nl == 1) ? w2p : w3p;
      const int ncalls = (nl == 2 && ns == 2) ? 11 : 16;
      stage_copy((const char*)src + ns*16128, lds + ((j+1)&1)*16384, ncalls, wave, lane);
    }
    if(sub == 0){
      // load this layer's act fragments (per-wave private; written by previous layer)
      #pragma unroll
      for(int ki = 0; ki < 4; ++ki)
        hf[ki] = *(const bf16x8*)(actW + m*SA + ki*32 + quad*8);
      const unsigned short* p4 = (quad < 3) ? (actW + m*SA + 128 + quad*8)
                                            : (const unsigned short*)ZB;
      hf[4] = *(const bf16x8*)p4;
    }
    const unsigned short* W = (const unsigned short*)(lds + (j&1)*16384);
    const int ntc = (layer == 2 && sub == 2) ? 2 : 3;
    const float* bias = (layer == 0) ? b1p : (layer == 1) ? b2p : b3p;
    #pragma unroll
    for(int jj = 0; jj < 3; ++jj){
      if(jj < ntc){
        const int rb = sub*48 + jj*16 + m;
        f32x4 acc = {0.f,0.f,0.f,0.f};
        #pragma unroll
        for(int ki = 0; ki < 5; ++ki){
          bf16x8 wf = *(const bf16x8*)(W + (jj*16 + m)*SH + ki*32 + quad*8);
          acc = __builtin_amdgcn_mfma_f32_16x16x32_bf16(hf[ki], wf, acc, 0, 0, 0);
        }
        float b = bias[rb];
        if(layer < 2){
          #pragma unroll
          for(int rr = 0; rr < 4; ++rr){
            float v = acc[rr] + b;
            v = v > 0.f ? v : 0.f;
            actW[(quad*4 + rr)*SA + rb] = f2b(v);
          }
        } else {
          #pragma unroll
          for(int rr = 0; rr < 4; ++rr)
            out[(size_t)(rowBase + quad*4 + rr)*DD + rb] = acc[rr] + b;
        }
      }
    }
    __syncthreads();                     // releases buf(j&1), drains slice j+1 DMA
  }
}

extern "C" void kernel_launch(void* const* d_in, const int* in_sizes, int n_in,
                              void* d_out, int out_size, void* d_ws, size_t ws_size,
                              hipStream_t stream){
  const float* signal = (const float*)d_in[0];
  const float* comps  = (const float*)d_in[1];
  const float* Wm = (const float*)d_in[2];
  const float* bm = (const float*)d_in[3];
  const float* Wu = (const float*)d_in[4];
  const float* bu = (const float*)d_in[5];
  const float* W0 = (const float*)d_in[6];
  const float* b0 = (const float*)d_in[7];
  const float* W1 = (const float*)d_in[8];
  const float* b1 = (const float*)d_in[9];
  const float* W2 = (const float*)d_in[10];
  const float* b2 = (const float*)d_in[11];
  const float* W3 = (const float*)d_in[12];
  const float* b3 = (const float*)d_in[13];

  char* ws = (char*)d_ws;
  float*          Wf   = (float*)(ws + 0);                 // 65536
  float*          bfv  = (float*)(ws + 65536);             // 512
  unsigned short* wAB  = (unsigned short*)(ws + 66048);    // 81920
  unsigned short* w1p  = (unsigned short*)(ws + 147968);   // 49152
  unsigned short* w2p  = (unsigned short*)(ws + 197120);   // 49152
  unsigned short* w3p  = (unsigned short*)(ws + 246272);   // 49152
  float*          b0p  = (float*)(ws + 295424);            // 576
  float*          b1p  = (float*)(ws + 296000);
  float*          b2p  = (float*)(ws + 296576);
  float*          b3p  = (float*)(ws + 297152);            // 512

  hipLaunchKernelGGL(prepA, dim3(64), dim3(256), 0, stream, Wm, bm, Wu, bu, Wf, bfv);

  // items: 20480+20480+24576+24576+24576+144+144+144+128 = 115248 -> 451 blocks
  hipLaunchKernelGGL(prepB, dim3(451), dim3(256), 0, stream,
                     W0, b0, W1, b1, W2, b2, W3, b3, Wf, bfv,
                     wAB, w1p, w2p, w3p, b0p, b1p, b2p, b3p);

  hipLaunchKernelGGL(fused_all, dim3(BB/128), dim3(512), 0, stream,
                     signal, comps, wAB, w1p, w2p, w3p,
                     b0p, b1p, b2p, b3p, (float*)d_out);
}

// Round 5
// 444.930 us; speedup vs baseline: 1.1819x; 1.1819x over previous
//
#include <hip/hip_runtime.h>
#include <stdint.h>

// Problem constants
#define DD  128     // latent dim
#define HH  132     // FCBlock hidden width
#define BB  65536   // batch
#define KKC 8       // num components
#define SW  136     // row stride (elems) for K=128 weight arrays (L0)
#define SH  168     // row stride (elems) for K=160 weight arrays (hidden)
#define SA  152     // act row stride (elems): cols 0..143 real, 144..151 zero

typedef short bf16x8 __attribute__((ext_vector_type(8)));
typedef short bf16x4 __attribute__((ext_vector_type(4)));
typedef float f32x4  __attribute__((ext_vector_type(4)));

__device__ __forceinline__ unsigned short f2b(float f){
  union{float f; unsigned u;} c; c.f = f;
  unsigned r = c.u + 0x7fffu + ((c.u >> 16) & 1u);   // RNE
  return (unsigned short)(r >> 16);
}

// ---------------- prep A: Wf = Wu @ Wm (fp32), bfv = K*(Wu@bm) + bu ----------------
__global__ void prepA(const float* __restrict__ Wm, const float* __restrict__ bm,
                      const float* __restrict__ Wu, const float* __restrict__ bu,
                      float* __restrict__ Wf, float* __restrict__ bfv){
  int idx = blockIdx.x * 256 + threadIdx.x;      // 64 blocks -> 16384 = 128*128
  int i = idx >> 7, j = idx & 127;
  float acc = 0.f;
  for(int d = 0; d < DD; ++d)
    acc += Wu[i*DD + d] * Wm[d*DD + j];
  Wf[idx] = acc;
  if(j == 0){
    float a = 0.f;
    for(int d = 0; d < DD; ++d) a += Wu[i*DD + d] * bm[d];
    bfv[i] = (float)KKC * a + bu[i];
  }
}

// ---------------- prep B: fused + padded + re-strided bf16 weights ----------------
// wAB = [w0s (20480 el, rows 144 x stride 136) | w0r (same)]
// w1p/w2p: 24576 el, rows 144 x stride 168 (cols >=132 zero)
// w3p:     24576 el, rows 128 x stride 168
__global__ void prepB(const float* __restrict__ W0, const float* __restrict__ b0,
                      const float* __restrict__ W1, const float* __restrict__ b1,
                      const float* __restrict__ W2, const float* __restrict__ b2,
                      const float* __restrict__ W3, const float* __restrict__ b3,
                      const float* __restrict__ Wf, const float* __restrict__ bfv,
                      unsigned short* __restrict__ wAB,
                      unsigned short* __restrict__ w1p, unsigned short* __restrict__ w2p,
                      unsigned short* __restrict__ w3p,
                      float* __restrict__ b0p, float* __restrict__ b1p,
                      float* __restrict__ b2p, float* __restrict__ b3p){
  int idx = blockIdx.x * 256 + threadIdx.x;
  if(idx < 20480){                                  // w0s: signal half of W0
    int n = idx / SW, c = idx % SW;
    wAB[idx] = (n < HH && c < DD) ? f2b(W0[n*(2*DD) + c]) : (unsigned short)0;
    return;
  }
  idx -= 20480;
  if(idx < 20480){                                  // w0r = W0r @ Wf
    int n = idx / SW, c = idx % SW;
    float acc = 0.f;
    bool live = (n < HH && c < DD);
    if(live)
      for(int i = 0; i < DD; ++i)
        acc += W0[n*(2*DD) + DD + i] * Wf[i*DD + c];
    wAB[20480 + idx] = live ? f2b(acc) : (unsigned short)0;
    return;
  }
  idx -= 20480;
  if(idx < 24576){                                  // w1p
    int n = idx / SH, c = idx % SH;
    w1p[idx] = (n < HH && c < HH) ? f2b(W1[n*HH + c]) : (unsigned short)0;
    return;
  }
  idx -= 24576;
  if(idx < 24576){                                  // w2p
    int n = idx / SH, c = idx % SH;
    w2p[idx] = (n < HH && c < HH) ? f2b(W2[n*HH + c]) : (unsigned short)0;
    return;
  }
  idx -= 24576;
  if(idx < 24576){                                  // w3p
    int n = idx / SH, c = idx % SH;
    w3p[idx] = (n < DD && c < HH) ? f2b(W3[n*HH + c]) : (unsigned short)0;
    return;
  }
  idx -= 24576;
  if(idx < 144){                                    // b0p = b0 + W0r @ bfv
    float acc = 0.f;
    if(idx < HH){
      acc = b0[idx];
      for(int i = 0; i < DD; ++i) acc += W0[idx*(2*DD) + DD + i] * bfv[i];
    }
    b0p[idx] = acc;
    return;
  }
  idx -= 144;
  if(idx < 144){ b1p[idx] = (idx < HH) ? b1[idx] : 0.f; return; }
  idx -= 144;
  if(idx < 144){ b2p[idx] = (idx < HH) ? b2[idx] : 0.f; return; }
  idx -= 144;
  if(idx < DD){ b3p[idx] = b3[idx]; return; }
}

// ---- async global->LDS: one call = this wave copies 1024B (lane*16 each) ----
__device__ __forceinline__ void stage_copy(const void* gsrc, void* ldst,
                                           int ncalls, int wave, int lane){
  const unsigned char* g = (const unsigned char*)gsrc + lane*16;
  unsigned char* l = (unsigned char*)ldst;
  for(int c = wave; c < ncalls; c += 8){
    __builtin_amdgcn_global_load_lds(
      (const __attribute__((address_space(1))) unsigned int*)(g + c*1024),
      (__attribute__((address_space(3))) unsigned int*)(l + c*1024),
      16, 0, 0);
  }
}

// ---------------- fused: component-sum + 4-layer MLP, one pass over HBM ------------
// 512 threads = 8 waves, 128 rows/block, grid 512, 2 blocks/CU (LDS 71712, VGPR<=128).
// ROUND-2 FIX: k-loop of the component sum is `#pragma unroll 1`. Full unroll made
// the scheduler hoist 64 independent global_load_dwordx4 (256 result VGPRs) past the
// 128-reg launch_bounds cap -> ~800 B/thread scratch spill (206 MB extra WRITE_SIZE,
// 2.4 TB/s). unroll 1 caps in-flight loads at <=2 iterations (<=64 regs), no spill.
// LDS: [0,32768) weight slices; [32768,71680) act (8 waves x 16 x 152); [71680,+32) zeros.
__global__ __launch_bounds__(512, 4) void fused_all(
    const float* __restrict__ signal,
    const float* __restrict__ comps,
    const unsigned short* __restrict__ wAB,
    const unsigned short* __restrict__ w1p,
    const unsigned short* __restrict__ w2p,
    const unsigned short* __restrict__ w3p,
    const float* __restrict__ b0p, const float* __restrict__ b1p,
    const float* __restrict__ b2p, const float* __restrict__ b3p,
    float* __restrict__ out)
{
  __shared__ __align__(16) unsigned char lds[71712];
  unsigned short* R   = (unsigned short*)lds;              // weight slices
  unsigned short* ACT = (unsigned short*)(lds + 32768);    // activations
  unsigned short* ZB  = (unsigned short*)(lds + 71680);    // 16 zero bf16

  const int t    = threadIdx.x;       // 0..511
  const int lane = t & 63;
  const int wave = t >> 6;            // 0..7
  const int m    = lane & 15;
  const int quad = lane >> 4;
  const int rowBase = blockIdx.x * 128 + wave * 16;
  const int arow = rowBase + m;
  unsigned short* actW = ACT + wave * 16 * SA;   // per-wave private 16x152 tile

  // issue L0 slice 0 (w0s rows 0..47 -> R[0,13312); w0r rows 0..47 -> R[13312,26624))
  stage_copy((const char*)wAB,          lds,          13, wave, lane);
  stage_copy((const char*)wAB + 40960,  lds + 13312,  13, wave, lane);

  // ---- component sum (fp32 accumulate, same per-element order as before) ----
  f32x4 cs[8];
  #pragma unroll
  for(int i = 0; i < 8; ++i) cs[i] = (f32x4){0.f,0.f,0.f,0.f};
  {
    const float* crow = comps + (size_t)arow * DD + quad*8;
    #pragma unroll 1
    for(int k = 0; k < KKC; ++k){
      const float* p = crow + (size_t)k * BB * DD;
      #pragma unroll
      for(int ki = 0; ki < 4; ++ki){
        cs[2*ki]   += *(const f32x4*)(p + ki*32);
        cs[2*ki+1] += *(const f32x4*)(p + ki*32 + 4);
      }
    }
  }
  bf16x8 sumf[4];
  #pragma unroll
  for(int ki = 0; ki < 4; ++ki){
    bf16x8 pk;
    #pragma unroll
    for(int j = 0; j < 4; ++j){ pk[j] = (short)f2b(cs[2*ki][j]); pk[4+j] = (short)f2b(cs[2*ki+1][j]); }
    sumf[ki] = pk;
  }

  // ---- signal fragment ----
  bf16x8 sigf[4];
  {
    const float* srow = signal + (size_t)arow * DD + quad*8;
    #pragma unroll
    for(int ki = 0; ki < 4; ++ki){
      f32x4 a = *(const f32x4*)(srow + ki*32);
      f32x4 b = *(const f32x4*)(srow + ki*32 + 4);
      bf16x8 pk;
      #pragma unroll
      for(int j = 0; j < 4; ++j){ pk[j] = (short)f2b(a[j]); pk[4+j] = (short)f2b(b[j]); }
      sigf[ki] = pk;
    }
  }

  // zero act pad cols [144,152) (128 rows x 8 cols = 512 uint writes) + zero buffer
  {
    int row = t >> 2, p = t & 3;
    *(unsigned*)(lds + 32768 + row*(SA*2) + 288 + p*4) = 0u;
    if(t < 8) ((unsigned*)ZB)[t] = 0u;
  }

  __syncthreads();   // drains L0 slice0 DMA + comp loads; publishes zeros

  // ---- layer 0: 3 slices of 48 rows, single-buffered ----
  #pragma unroll
  for(int s = 0; s < 3; ++s){
    #pragma unroll
    for(int jj = 0; jj < 3; ++jj){
      const int r  = jj*16 + m;          // row within slice
      const int rb = s*48 + jj*16 + m;   // global weight row / act col
      f32x4 acc = {0.f,0.f,0.f,0.f};
      #pragma unroll
      for(int ki = 0; ki < 4; ++ki){
        bf16x8 wf = *(const bf16x8*)(R + r*SW + ki*32 + quad*8);
        acc = __builtin_amdgcn_mfma_f32_16x16x32_bf16(sigf[ki], wf, acc, 0, 0, 0);
      }
      #pragma unroll
      for(int ki = 0; ki < 4; ++ki){
        bf16x8 wf = *(const bf16x8*)(R + 6656 + r*SW + ki*32 + quad*8);
        acc = __builtin_amdgcn_mfma_f32_16x16x32_bf16(sumf[ki], wf, acc, 0, 0, 0);
      }
      float bias = b0p[rb];
      #pragma unroll
      for(int rr = 0; rr < 4; ++rr){
        float v = acc[rr] + bias;
        v = v > 0.f ? v : 0.f;
        actW[(quad*4 + rr)*SA + rb] = f2b(v);
      }
    }
    __syncthreads();                     // all waves done reading R
    if(s == 0){
      stage_copy((const char*)wAB + 13056,          lds,         13, wave, lane);
      stage_copy((const char*)wAB + 40960 + 13056,  lds + 13312, 13, wave, lane);
    } else if(s == 1){
      stage_copy((const char*)wAB + 26112,          lds,         13, wave, lane);
      stage_copy((const char*)wAB + 40960 + 26112,  lds + 13312, 13, wave, lane);
    } else {
      stage_copy((const char*)w1p, lds, 16, wave, lane);   // L1 slice0 -> buf0
    }
    __syncthreads();                     // drains the DMA just issued
  }

  // ---- hidden layers: 9 slices (L1 s0..2, L2 s0..2, L3 s0..2), double-buffered ----
  bf16x8 hf[5];
  #pragma unroll
  for(int j = 0; j < 9; ++j){
    const int layer = j / 3, sub = j - layer*3;
    // issue slice j+1 into the other buffer (overlaps with compute below)
    if(j < 8){
      const int nl = (j+1) / 3, ns = (j+1) - nl*3;
      const unsigned short* src = (nl == 0) ? w1p : (nl == 1) ? w2p : w3p;
      const int ncalls = (nl == 2 && ns == 2) ? 11 : 16;
      stage_copy((const char*)src + ns*16128, lds + ((j+1)&1)*16384, ncalls, wave, lane);
    }
    if(sub == 0){
      // load this layer's act fragments (per-wave private; written by previous layer)
      #pragma unroll
      for(int ki = 0; ki < 4; ++ki)
        hf[ki] = *(const bf16x8*)(actW + m*SA + ki*32 + quad*8);
      const unsigned short* p4 = (quad < 3) ? (actW + m*SA + 128 + quad*8)
                                            : (const unsigned short*)ZB;
      hf[4] = *(const bf16x8*)p4;
    }
    const unsigned short* W = (const unsigned short*)(lds + (j&1)*16384);
    const int ntc = (layer == 2 && sub == 2) ? 2 : 3;
    const float* bias = (layer == 0) ? b1p : (layer == 1) ? b2p : b3p;
    #pragma unroll
    for(int jj = 0; jj < 3; ++jj){
      if(jj < ntc){
        const int rb = sub*48 + jj*16 + m;
        f32x4 acc = {0.f,0.f,0.f,0.f};
        #pragma unroll
        for(int ki = 0; ki < 5; ++ki){
          bf16x8 wf = *(const bf16x8*)(W + (jj*16 + m)*SH + ki*32 + quad*8);
          acc = __builtin_amdgcn_mfma_f32_16x16x32_bf16(hf[ki], wf, acc, 0, 0, 0);
        }
        float b = bias[rb];
        if(layer < 2){
          #pragma unroll
          for(int rr = 0; rr < 4; ++rr){
            float v = acc[rr] + b;
            v = v > 0.f ? v : 0.f;
            actW[(quad*4 + rr)*SA + rb] = f2b(v);
          }
        } else {
          #pragma unroll
          for(int rr = 0; rr < 4; ++rr)
            out[(size_t)(rowBase + quad*4 + rr)*DD + rb] = acc[rr] + b;
        }
      }
    }
    __syncthreads();                     // releases buf(j&1), drains slice j+1 DMA
  }
}

extern "C" void kernel_launch(void* const* d_in, const int* in_sizes, int n_in,
                              void* d_out, int out_size, void* d_ws, size_t ws_size,
                              hipStream_t stream){
  const float* signal = (const float*)d_in[0];
  const float* comps  = (const float*)d_in[1];
  const float* Wm = (const float*)d_in[2];
  const float* bm = (const float*)d_in[3];
  const float* Wu = (const float*)d_in[4];
  const float* bu = (const float*)d_in[5];
  const float* W0 = (const float*)d_in[6];
  const float* b0 = (const float*)d_in[7];
  const float* W1 = (const float*)d_in[8];
  const float* b1 = (const float*)d_in[9];
  const float* W2 = (const float*)d_in[10];
  const float* b2 = (const float*)d_in[11];
  const float* W3 = (const float*)d_in[12];
  const float* b3 = (const float*)d_in[13];

  char* ws = (char*)d_ws;
  float*          Wf   = (float*)(ws + 0);                 // 65536
  float*          bfv  = (float*)(ws + 65536);             // 512
  unsigned short* wAB  = (unsigned short*)(ws + 66048);    // 81920
  unsigned short* w1p  = (unsigned short*)(ws + 147968);   // 49152
  unsigned short* w2p  = (unsigned short*)(ws + 197120);   // 49152
  unsigned short* w3p  = (unsigned short*)(ws + 246272);   // 49152
  float*          b0p  = (float*)(ws + 295424);            // 576
  float*          b1p  = (float*)(ws + 296000);
  float*          b2p  = (float*)(ws + 296576);
  float*          b3p  = (float*)(ws + 297152);            // 512

  hipLaunchKernelGGL(prepA, dim3(64), dim3(256), 0, stream, Wm, bm, Wu, bu, Wf, bfv);

  // items: 20480+20480+24576+24576+24576+144+144+144+128 = 115248 -> 451 blocks
  hipLaunchKernelGGL(prepB, dim3(451), dim3(256), 0, stream,
                     W0, b0, W1, b1, W2, b2, W3, b3, Wf, bfv,
                     wAB, w1p, w2p, w3p, b0p, b1p, b2p, b3p);

  hipLaunchKernelGGL(fused_all, dim3(BB/128), dim3(512), 0, stream,
                     signal, comps, wAB, w1p, w2p, w3p,
                     b0p, b1p, b2p, b3p, (float*)d_out);
}

// Round 7
// 444.265 us; speedup vs baseline: 1.1837x; 1.0015x over previous
//
#include <hip/hip_runtime.h>
#include <stdint.h>

// Problem constants
#define DD  128     // latent dim
#define HH  132     // FCBlock hidden width
#define BB  65536   // batch
#define KKC 8       // num components
#define SW  136     // row stride (elems) for K=128 weight arrays (L0)
#define SH  168     // row stride (elems) for K=160 weight arrays (hidden)
#define SA  152     // act row stride (elems): cols 0..143 real, 144..151 zero
#define WAVES 4     // waves per block (round-6: was 8)
#define RPB  64     // rows per block = WAVES*16

typedef short bf16x8 __attribute__((ext_vector_type(8)));
typedef short bf16x4 __attribute__((ext_vector_type(4)));
typedef float f32x4  __attribute__((ext_vector_type(4)));

__device__ __forceinline__ unsigned short f2b(float f){
  union{float f; unsigned u;} c; c.f = f;
  unsigned r = c.u + 0x7fffu + ((c.u >> 16) & 1u);   // RNE
  return (unsigned short)(r >> 16);
}

// ---------------- prep A: Wf = Wu @ Wm (fp32), bfv = K*(Wu@bm) + bu ----------------
__global__ void prepA(const float* __restrict__ Wm, const float* __restrict__ bm,
                      const float* __restrict__ Wu, const float* __restrict__ bu,
                      float* __restrict__ Wf, float* __restrict__ bfv){
  int idx = blockIdx.x * 256 + threadIdx.x;      // 64 blocks -> 16384 = 128*128
  int i = idx >> 7, j = idx & 127;
  float acc = 0.f;
  for(int d = 0; d < DD; ++d)
    acc += Wu[i*DD + d] * Wm[d*DD + j];
  Wf[idx] = acc;
  if(j == 0){
    float a = 0.f;
    for(int d = 0; d < DD; ++d) a += Wu[i*DD + d] * bm[d];
    bfv[i] = (float)KKC * a + bu[i];
  }
}

// ---------------- prep B: fused + padded + re-strided bf16 weights ----------------
// wAB = [w0s (20480 el, rows 144 x stride 136) | w0r (same)]
// w1p/w2p: 24576 el, rows 144 x stride 168 (cols >=132 zero)
// w3p:     24576 el, rows 128 x stride 168
__global__ void prepB(const float* __restrict__ W0, const float* __restrict__ b0,
                      const float* __restrict__ W1, const float* __restrict__ b1,
                      const float* __restrict__ W2, const float* __restrict__ b2,
                      const float* __restrict__ W3, const float* __restrict__ b3,
                      const float* __restrict__ Wf, const float* __restrict__ bfv,
                      unsigned short* __restrict__ wAB,
                      unsigned short* __restrict__ w1p, unsigned short* __restrict__ w2p,
                      unsigned short* __restrict__ w3p,
                      float* __restrict__ b0p, float* __restrict__ b1p,
                      float* __restrict__ b2p, float* __restrict__ b3p){
  int idx = blockIdx.x * 256 + threadIdx.x;
  if(idx < 20480){                                  // w0s: signal half of W0
    int n = idx / SW, c = idx % SW;
    wAB[idx] = (n < HH && c < DD) ? f2b(W0[n*(2*DD) + c]) : (unsigned short)0;
    return;
  }
  idx -= 20480;
  if(idx < 20480){                                  // w0r = W0r @ Wf
    int n = idx / SW, c = idx % SW;
    float acc = 0.f;
    bool live = (n < HH && c < DD);
    if(live)
      for(int i = 0; i < DD; ++i)
        acc += W0[n*(2*DD) + DD + i] * Wf[i*DD + c];
    wAB[20480 + idx] = live ? f2b(acc) : (unsigned short)0;
    return;
  }
  idx -= 20480;
  if(idx < 24576){                                  // w1p
    int n = idx / SH, c = idx % SH;
    w1p[idx] = (n < HH && c < HH) ? f2b(W1[n*HH + c]) : (unsigned short)0;
    return;
  }
  idx -= 24576;
  if(idx < 24576){                                  // w2p
    int n = idx / SH, c = idx % SH;
    w2p[idx] = (n < HH && c < HH) ? f2b(W2[n*HH + c]) : (unsigned short)0;
    return;
  }
  idx -= 24576;
  if(idx < 24576){                                  // w3p
    int n = idx / SH, c = idx % SH;
    w3p[idx] = (n < DD && c < HH) ? f2b(W3[n*HH + c]) : (unsigned short)0;
    return;
  }
  idx -= 24576;
  if(idx < 144){                                    // b0p = b0 + W0r @ bfv
    float acc = 0.f;
    if(idx < HH){
      acc = b0[idx];
      for(int i = 0; i < DD; ++i) acc += W0[idx*(2*DD) + DD + i] * bfv[i];
    }
    b0p[idx] = acc;
    return;
  }
  idx -= 144;
  if(idx < 144){ b1p[idx] = (idx < HH) ? b1[idx] : 0.f; return; }
  idx -= 144;
  if(idx < 144){ b2p[idx] = (idx < HH) ? b2[idx] : 0.f; return; }
  idx -= 144;
  if(idx < DD){ b3p[idx] = b3[idx]; return; }
}

// ---- async global->LDS: one call = this wave copies 1024B (lane*16 each) ----
__device__ __forceinline__ void stage_copy(const void* gsrc, void* ldst,
                                           int ncalls, int wave, int lane){
  const unsigned char* g = (const unsigned char*)gsrc + lane*16;
  unsigned char* l = (unsigned char*)ldst;
  for(int c = wave; c < ncalls; c += WAVES){
    __builtin_amdgcn_global_load_lds(
      (const __attribute__((address_space(1))) unsigned int*)(g + c*1024),
      (__attribute__((address_space(3))) unsigned int*)(l + c*1024),
      16, 0, 0);
  }
}

// ---------------- fused: component-sum + 4-layer MLP, one pass over HBM ------------
// ROUND-6 GEOMETRY CHANGE: 1024 blocks x 256 threads (4 waves, 64 rows/block),
// LDS 52256 B -> 3 blocks/CU (was 512x512, 2 blocks/CU). Rationale: the 512-grid
// was exactly-resident and phase-lockstepped (all CUs stream comps, then all do
// the LDS/MFMA phase) -> phase transitions and barrier drains add instead of hide.
// With 768 resident + 256 ragged blocks, late blocks stream comps while early
// blocks run their MLP phase. Per-wave work/order identical -> bit-identical out.
// ROUND-2 FIX retained: component-sum k-loop is `#pragma unroll 1` (VGPR spill).
// LDS: [0,32768) weight slices; [32768,52224) act (4 waves x 16 x 152); [52224,+32) zeros.
__global__ __launch_bounds__(256, 4) void fused_all(
    const float* __restrict__ signal,
    const float* __restrict__ comps,
    const unsigned short* __restrict__ wAB,
    const unsigned short* __restrict__ w1p,
    const unsigned short* __restrict__ w2p,
    const unsigned short* __restrict__ w3p,
    const float* __restrict__ b0p, const float* __restrict__ b1p,
    const float* __restrict__ b2p, const float* __restrict__ b3p,
    float* __restrict__ out)
{
  __shared__ __align__(16) unsigned char lds[52256];
  unsigned short* R   = (unsigned short*)lds;              // weight slices
  unsigned short* ACT = (unsigned short*)(lds + 32768);    // activations
  unsigned short* ZB  = (unsigned short*)(lds + 52224);    // 16 zero bf16

  const int t    = threadIdx.x;       // 0..255
  const int lane = t & 63;
  const int wave = t >> 6;            // 0..3
  const int m    = lane & 15;
  const int quad = lane >> 4;
  const int rowBase = blockIdx.x * RPB + wave * 16;
  const int arow = rowBase + m;
  unsigned short* actW = ACT + wave * 16 * SA;   // per-wave private 16x152 tile

  // issue L0 slice 0 (w0s rows 0..47 -> R[0,13312); w0r rows 0..47 -> R[13312,26624))
  stage_copy((const char*)wAB,          lds,          13, wave, lane);
  stage_copy((const char*)wAB + 40960,  lds + 13312,  13, wave, lane);

  // ---- component sum (fp32 accumulate, same per-element order as before) ----
  f32x4 cs[8];
  #pragma unroll
  for(int i = 0; i < 8; ++i) cs[i] = (f32x4){0.f,0.f,0.f,0.f};
  {
    const float* crow = comps + (size_t)arow * DD + quad*8;
    #pragma unroll 1
    for(int k = 0; k < KKC; ++k){
      const float* p = crow + (size_t)k * BB * DD;
      #pragma unroll
      for(int ki = 0; ki < 4; ++ki){
        cs[2*ki]   += *(const f32x4*)(p + ki*32);
        cs[2*ki+1] += *(const f32x4*)(p + ki*32 + 4);
      }
    }
  }
  bf16x8 sumf[4];
  #pragma unroll
  for(int ki = 0; ki < 4; ++ki){
    bf16x8 pk;
    #pragma unroll
    for(int j = 0; j < 4; ++j){ pk[j] = (short)f2b(cs[2*ki][j]); pk[4+j] = (short)f2b(cs[2*ki+1][j]); }
    sumf[ki] = pk;
  }

  // ---- signal fragment ----
  bf16x8 sigf[4];
  {
    const float* srow = signal + (size_t)arow * DD + quad*8;
    #pragma unroll
    for(int ki = 0; ki < 4; ++ki){
      f32x4 a = *(const f32x4*)(srow + ki*32);
      f32x4 b = *(const f32x4*)(srow + ki*32 + 4);
      bf16x8 pk;
      #pragma unroll
      for(int j = 0; j < 4; ++j){ pk[j] = (short)f2b(a[j]); pk[4+j] = (short)f2b(b[j]); }
      sigf[ki] = pk;
    }
  }

  // zero act K-pad cols [144,152): 64 rows x 8 cols x 2B = 256 dwords; + zero buffer
  {
    int row = t >> 2, p = t & 3;                    // 64 rows, 4 dwords each
    *(unsigned*)(lds + 32768 + row*(SA*2) + 288 + p*4) = 0u;
    if(t < 8) ((unsigned*)ZB)[t] = 0u;
  }

  __syncthreads();   // drains L0 slice0 DMA + comp loads; publishes zeros

  // ---- layer 0: 3 slices of 48 rows, single-buffered ----
  #pragma unroll
  for(int s = 0; s < 3; ++s){
    #pragma unroll
    for(int jj = 0; jj < 3; ++jj){
      const int r  = jj*16 + m;          // row within slice
      const int rb = s*48 + jj*16 + m;   // global weight row / act col
      f32x4 acc = {0.f,0.f,0.f,0.f};
      #pragma unroll
      for(int ki = 0; ki < 4; ++ki){
        bf16x8 wf = *(const bf16x8*)(R + r*SW + ki*32 + quad*8);
        acc = __builtin_amdgcn_mfma_f32_16x16x32_bf16(sigf[ki], wf, acc, 0, 0, 0);
      }
      #pragma unroll
      for(int ki = 0; ki < 4; ++ki){
        bf16x8 wf = *(const bf16x8*)(R + 6656 + r*SW + ki*32 + quad*8);
        acc = __builtin_amdgcn_mfma_f32_16x16x32_bf16(sumf[ki], wf, acc, 0, 0, 0);
      }
      float bias = b0p[rb];
      #pragma unroll
      for(int rr = 0; rr < 4; ++rr){
        float v = acc[rr] + bias;
        v = v > 0.f ? v : 0.f;
        actW[(quad*4 + rr)*SA + rb] = f2b(v);
      }
    }
    __syncthreads();                     // all waves done reading R
    if(s == 0){
      stage_copy((const char*)wAB + 13056,          lds,         13, wave, lane);
      stage_copy((const char*)wAB + 40960 + 13056,  lds + 13312, 13, wave, lane);
    } else if(s == 1){
      stage_copy((const char*)wAB + 26112,          lds,         13, wave, lane);
      stage_copy((const char*)wAB + 40960 + 26112,  lds + 13312, 13, wave, lane);
    } else {
      stage_copy((const char*)w1p, lds, 16, wave, lane);   // L1 slice0 -> buf0
    }
    __syncthreads();                     // drains the DMA just issued
  }

  // ---- hidden layers: 9 slices (L1 s0..2, L2 s0..2, L3 s0..2), double-buffered ----
  bf16x8 hf[5];
  #pragma unroll
  for(int j = 0; j < 9; ++j){
    const int layer = j / 3, sub = j - layer*3;
    // issue slice j+1 into the other buffer (overlaps with compute below)
    if(j < 8){
      const int nl = (j+1) / 3, ns = (j+1) - nl*3;
      const unsigned short* src = (nl == 0) ? w1p : (nl == 1) ? w2p : w3p;
      const int ncalls = (nl == 2 && ns == 2) ? 11 : 16;
      stage_copy((const char*)src + ns*16128, lds + ((j+1)&1)*16384, ncalls, wave, lane);
    }
    if(sub == 0){
      // load this layer's act fragments (per-wave private; written by previous layer)
      #pragma unroll
      for(int ki = 0; ki < 4; ++ki)
        hf[ki] = *(const bf16x8*)(actW + m*SA + ki*32 + quad*8);
      const unsigned short* p4 = (quad < 3) ? (actW + m*SA + 128 + quad*8)
                                            : (const unsigned short*)ZB;
      hf[4] = *(const bf16x8*)p4;
    }
    const unsigned short* W = (const unsigned short*)(lds + (j&1)*16384);
    const int ntc = (layer == 2 && sub == 2) ? 2 : 3;
    const float* bias = (layer == 0) ? b1p : (layer == 1) ? b2p : b3p;
    #pragma unroll
    for(int jj = 0; jj < 3; ++jj){
      if(jj < ntc){
        const int rb = sub*48 + jj*16 + m;
        f32x4 acc = {0.f,0.f,0.f,0.f};
        #pragma unroll
        for(int ki = 0; ki < 5; ++ki){
          bf16x8 wf = *(const bf16x8*)(W + (jj*16 + m)*SH + ki*32 + quad*8);
          acc = __builtin_amdgcn_mfma_f32_16x16x32_bf16(hf[ki], wf, acc, 0, 0, 0);
        }
        float b = bias[rb];
        if(layer < 2){
          #pragma unroll
          for(int rr = 0; rr < 4; ++rr){
            float v = acc[rr] + b;
            v = v > 0.f ? v : 0.f;
            actW[(quad*4 + rr)*SA + rb] = f2b(v);
          }
        } else {
          #pragma unroll
          for(int rr = 0; rr < 4; ++rr)
            out[(size_t)(rowBase + quad*4 + rr)*DD + rb] = acc[rr] + b;
        }
      }
    }
    __syncthreads();                     // releases buf(j&1), drains slice j+1 DMA
  }
}

extern "C" void kernel_launch(void* const* d_in, const int* in_sizes, int n_in,
                              void* d_out, int out_size, void* d_ws, size_t ws_size,
                              hipStream_t stream){
  const float* signal = (const float*)d_in[0];
  const float* comps  = (const float*)d_in[1];
  const float* Wm = (const float*)d_in[2];
  const float* bm = (const float*)d_in[3];
  const float* Wu = (const float*)d_in[4];
  const float* bu = (const float*)d_in[5];
  const float* W0 = (const float*)d_in[6];
  const float* b0 = (const float*)d_in[7];
  const float* W1 = (const float*)d_in[8];
  const float* b1 = (const float*)d_in[9];
  const float* W2 = (const float*)d_in[10];
  const float* b2 = (const float*)d_in[11];
  const float* W3 = (const float*)d_in[12];
  const float* b3 = (const float*)d_in[13];

  char* ws = (char*)d_ws;
  float*          Wf   = (float*)(ws + 0);                 // 65536
  float*          bfv  = (float*)(ws + 65536);             // 512
  unsigned short* wAB  = (unsigned short*)(ws + 66048);    // 81920
  unsigned short* w1p  = (unsigned short*)(ws + 147968);   // 49152
  unsigned short* w2p  = (unsigned short*)(ws + 197120);   // 49152
  unsigned short* w3p  = (unsigned short*)(ws + 246272);   // 49152
  float*          b0p  = (float*)(ws + 295424);            // 576
  float*          b1p  = (float*)(ws + 296000);
  float*          b2p  = (float*)(ws + 296576);
  float*          b3p  = (float*)(ws + 297152);            // 512

  hipLaunchKernelGGL(prepA, dim3(64), dim3(256), 0, stream, Wm, bm, Wu, bu, Wf, bfv);

  // items: 20480+20480+24576+24576+24576+144+144+144+128 = 115248 -> 451 blocks
  hipLaunchKernelGGL(prepB, dim3(451), dim3(256), 0, stream,
                     W0, b0, W1, b1, W2, b2, W3, b3, Wf, bfv,
                     wAB, w1p, w2p, w3p, b0p, b1p, b2p, b3p);

  hipLaunchKernelGGL(fused_all, dim3(BB/RPB), dim3(256), 0, stream,
                     signal, comps, wAB, w1p, w2p, w3p,
                     b0p, b1p, b2p, b3p, (float*)d_out);
}